// Round 13
// baseline (132.031 us; speedup 1.0000x reference)
//
#include <hip/hip_runtime.h>
#include <cstdio>

// B=32, Cin=128, S=8192, H=4, Hc=32, M=64, Cout=128
#define S_LEN 8192
#define NM 64

typedef short s8v __attribute__((ext_vector_type(8)));   // 8 bf16
typedef float f4  __attribute__((ext_vector_type(4)));
typedef _Float16 h8 __attribute__((ext_vector_type(8))); // 8 fp16

static __device__ inline unsigned short f2bf(float f) {  // RNE fp32->bf16
    unsigned int u = __builtin_bit_cast(unsigned int, f);
    u = (u + 0x7FFFu + ((u >> 16) & 1u)) >> 16;
    return (unsigned short)u;
}
static __device__ inline float bf2f(unsigned short h) {
    unsigned int u = ((unsigned int)h) << 16;
    return __builtin_bit_cast(float, u);
}

// C2/T1-image swizzle: [128 r][32 k] tile, XOR k-bits 3..4 with (r>>1)&3
#define SW32(r, k) (((r) * 32) + ((k) ^ ((((r) >> 1) & 3) << 3)))

static __device__ __forceinline__ void glds16(const void* g, void* l) {
    __builtin_amdgcn_global_load_lds(
        (const __attribute__((address_space(1))) unsigned int*)g,
        (__attribute__((address_space(3))) unsigned int*)l, 16, 0, 0);
}

// ---------------- master trig table: tab[p] = cos(2*pi*p/8192) ----------------
__global__ __launch_bounds__(256) void gen_master(float* __restrict__ tab) {
    int p = blockIdx.x * 256 + threadIdx.x;
    tab[p] = cosf((float)p * (6.28318530717958647692f / (float)S_LEN));
}

// T1 image (K3's B^T): (s,k) k=2m|2m+1; img[(sb*4+kc)*4096 + SW32(s&127,k&31)]
// -sin(theta_p) == cos(theta_{p+2048})
__global__ __launch_bounds__(256) void gen_t1_img(const float* __restrict__ tab,
                                                  short* __restrict__ Th,
                                                  short* __restrict__ Tl) {
    int tid = blockIdx.x * 256 + threadIdx.x;     // 1M
    int tile = tid >> 12;
    int sb = tile >> 2, kc = tile & 3;
    int us = tid & 4095;
    int ls = us >> 5, kx = us & 31;
    int lk = kx ^ (((ls >> 1) & 3) << 3);
    int s = sb * 128 + ls;
    int k = kc * 32 + lk;
    int m = k >> 1;
    int p = (m * s + ((k & 1) << 11)) & (S_LEN - 1);
    float v = tab[p];                             // k odd -> -sin; k=1 -> 0 (Im(DC) dropped)
    unsigned short h = f2bf(v);
    Th[tid] = (short)h;
    Tl[tid] = (short)f2bf(v - bf2f(h));
}

// Bfrag (K1's B in MFMA-fragment order, fp16): [kstep 256][nf 8][lane 64][8] = 2MB.
// lane=(kq<<4)|rl -> col=nf*16+rl, k=kstep*32+kq*8+e; val=(col&1)?-sin:cos(2pi m k/S).
// (mapping numerically validated in R8)
__global__ __launch_bounds__(256) void gen_b_frag(const float* __restrict__ tab,
                                                  _Float16* __restrict__ Bf) {
    int tid = blockIdx.x * 256 + threadIdx.x;     // 1M
    int e = tid & 7;
    int lane = (tid >> 3) & 63;
    int nf = (tid >> 9) & 7;
    int kstep = tid >> 12;                        // 0..255
    int rl = lane & 15, kq = lane >> 4;
    int col = nf * 16 + rl;
    int m = col >> 1;
    int k = kstep * 32 + kq * 8 + e;
    int p = (m * k + ((col & 1) << 11)) & (S_LEN - 1);
    Bf[tid] = (_Float16)tab[p];
}

// ---------------- K1: P[ks] = x * B1 ; waveprivate: NO LDS, NO barriers ----------------
// Grid (64,8) x 256 thr: 2048 independent waves. Wave: 16 rows x 128 cols x K-chunk 1024.
// Per step (BK=32): A 2xf4 direct from x -> cvt fp16 hi/lo; B 8 frags from L2 image; 16 MFMA.
__global__ __launch_bounds__(256, 2) void dft_fwd_mfma(const float* __restrict__ x,
        const _Float16* __restrict__ Bf, float* __restrict__ P) {
    const int t = threadIdx.x;
    const int lane = t & 63, w = t >> 6;
    const int rl = lane & 15, kq = lane >> 4;
    const int mtile = blockIdx.x * 4 + w;         // 0..255
    const int ks = blockIdx.y;                    // 0..7
    const int row0 = mtile * 16;
    // A: this lane's fragment source: row row0+rl, k = ks*1024 + s*32 + kq*8 (+e)
    const size_t xbase = (size_t)(row0 + rl) * S_LEN + (size_t)ks * 1024 + (size_t)kq * 8;
    // B: fragment image bytes: kstep*8192 + nf*1024 + lane*16
    const char* bbase = (const char*)Bf + (size_t)ks * 32 * 8192 + (size_t)lane * 16;

    f4 acc[8];
    #pragma unroll
    for (int i = 0; i < 8; ++i) acc[i] = (f4){0.f, 0.f, 0.f, 0.f};

    #pragma unroll
    for (int s = 0; s < 32; ++s) {
        // A: 8 fp32 (this lane's k-slice) straight from HBM
        f4 a0 = *(const f4*)&x[xbase + (size_t)s * 32];
        f4 a1 = *(const f4*)&x[xbase + (size_t)s * 32 + 4];
        // B: 8 column-fragments from L2 (1KB contiguous per wave-instruction)
        h8 Bv[8];
        #pragma unroll
        for (int nf = 0; nf < 8; ++nf)
            Bv[nf] = *(const h8*)(bbase + (size_t)s * 8192 + (size_t)nf * 1024);
        // split fp32 -> fp16 hi + lo (exact residual)
        h8 Ah, Al;
        #pragma unroll
        for (int e = 0; e < 4; ++e) {
            float f = a0[e]; _Float16 hh = (_Float16)f;
            Ah[e] = hh; Al[e] = (_Float16)(f - (float)hh);
        }
        #pragma unroll
        for (int e = 0; e < 4; ++e) {
            float f = a1[e]; _Float16 hh = (_Float16)f;
            Ah[4 + e] = hh; Al[4 + e] = (_Float16)(f - (float)hh);
        }
        #pragma unroll
        for (int nf = 0; nf < 8; ++nf)
            acc[nf] = __builtin_amdgcn_mfma_f32_16x16x32_f16(Ah, Bv[nf], acc[nf], 0, 0, 0);
        #pragma unroll
        for (int nf = 0; nf < 8; ++nf)
            acc[nf] = __builtin_amdgcn_mfma_f32_16x16x32_f16(Al, Bv[nf], acc[nf], 0, 0, 0);
    }

    // D layout: col=lane&15, row=(lane>>4)*4+reg
    float* Pks = P + (size_t)ks * 524288;
    #pragma unroll
    for (int nf = 0; nf < 8; ++nf)
        #pragma unroll
        for (int r = 0; r < 4; ++r)
            Pks[(size_t)(row0 + kq * 4 + r) * 128 + nf * 16 + rl] = acc[nf][r];
}

// ---------------- ksum: X = sum of 8 P slices (coalesced) ----------------
__global__ __launch_bounds__(256) void ksum(const float* __restrict__ P,
                                            float* __restrict__ X) {
    int i = (blockIdx.x * 256 + threadIdx.x) * 4;
    f4 s = (f4){0.f, 0.f, 0.f, 0.f};
    #pragma unroll
    for (int ks = 0; ks < 8; ++ks)
        s += *(const f4*)&P[(size_t)ks * 524288 + i];
    *(f4*)&X[i] = s;
}

// ---------------- K2: mode contraction -> C2 image (pre-swizzled bf16 hi/lo) ----------------
__global__ __launch_bounds__(256) void mode_contract(const float* __restrict__ X,
        const float* __restrict__ w_real, const float* __restrict__ w_imag,
        short* __restrict__ C2h, short* __restrict__ C2l) {
    __shared__ float xr[32][128], xi[32][128];
    __shared__ float wr[128][32], wi[128][32];
    const int m = blockIdx.x, h = blockIdx.y, t = threadIdx.x;
    #pragma unroll
    for (int it = 0; it < 16; ++it) {
        int li = t + it * 256;       // 0..4095
        int b = li >> 7, i = li & 127;
        const float2 v = *(const float2*)&X[(size_t)(b * 128 + i) * 128 + 2 * m];
        xr[b][i] = v.x; xi[b][i] = v.y;
        int i2 = li >> 5, o = li & 31;
        size_t off = ((size_t)((h * 128 + i2) * 32 + o)) * NM + m;
        wr[i2][o] = w_real[off];
        wi[i2][o] = w_imag[off];
    }
    __syncthreads();
    const int o = t & 31;
    const int b0 = (t >> 5) * 4;
    float re[4] = {0.f, 0.f, 0.f, 0.f}, im[4] = {0.f, 0.f, 0.f, 0.f};
    for (int i = 0; i < 128; ++i) {
        float wrv = wr[i][o], wiv = wi[i][o];
        #pragma unroll
        for (int j = 0; j < 4; ++j) {
            float a = xr[b0 + j][i], c = xi[b0 + j][i];
            re[j] += a * wrv - c * wiv;
            im[j] += a * wiv + c * wrv;
        }
    }
    const float alpha = (m == 0) ? (1.0f / (float)S_LEN) : (2.0f / (float)S_LEN);
    const int kc = m >> 4;
    const int lk = (2 * m) & 31;
    #pragma unroll
    for (int j = 0; j < 4; ++j) {
        int row = (b0 + j) * 128 + h * 32 + o;
        float vr = alpha * re[j], vi = alpha * im[j];
        unsigned short hr = f2bf(vr), hi_ = f2bf(vi);
        float lr = vr - bf2f(hr), li_ = vi - bf2f(hi_);
        int rb = row >> 7, lr_ = row & 127;
        size_t ui = ((size_t)(rb * 4 + kc) * 4096 + SW32(lr_, lk)) >> 1;   // uint index
        ((unsigned int*)C2h)[ui] = ((unsigned int)hi_ << 16) | hr;
        ((unsigned int*)C2l)[ui] = ((unsigned int)f2bf(li_) << 16) | f2bf(lr);
    }
}

// ---------------- K3: y = C2[4096][128] * Basis[128][8192], dbuf DMA pipeline ----------------
__global__ __launch_bounds__(256, 2) void idft_mfma(const short* __restrict__ C2h,
        const short* __restrict__ C2l, const short* __restrict__ T1h,
        const short* __restrict__ T1l, float* __restrict__ y) {
    __shared__ short ah[2][4096], al[2][4096];
    __shared__ short bh[2][4096], bl[2][4096];
    const int t = threadIdx.x;
    const int lane = t & 63, wid = t >> 6;
    const int wm = (wid >> 1) * 64, wn = (wid & 1) * 64;
    const int sb = blockIdx.x;                    // col block (s), 0..63
    const int rb = blockIdx.y;                    // row block, 0..31
    f4 acc[4][4];
    #pragma unroll
    for (int i = 0; i < 4; ++i)
        #pragma unroll
        for (int j = 0; j < 4; ++j) acc[i][j] = (f4){0.f, 0.f, 0.f, 0.f};

    #define DMA3(kc, buf)  {                                                       \
        const size_t ta = (size_t)(rb * 4 + (kc)) * 8192;                          \
        const size_t tb = (size_t)(sb * 4 + (kc)) * 8192;                          \
        const int wo = wid * 2048 + lane * 16;                                     \
        glds16((const char*)C2h + ta + wo,        (char*)&ah[buf][0] + wid * 2048);        \
        glds16((const char*)C2h + ta + wo + 1024, (char*)&ah[buf][0] + wid * 2048 + 1024); \
        glds16((const char*)C2l + ta + wo,        (char*)&al[buf][0] + wid * 2048);        \
        glds16((const char*)C2l + ta + wo + 1024, (char*)&al[buf][0] + wid * 2048 + 1024); \
        glds16((const char*)T1h + tb + wo,        (char*)&bh[buf][0] + wid * 2048);        \
        glds16((const char*)T1h + tb + wo + 1024, (char*)&bh[buf][0] + wid * 2048 + 1024); \
        glds16((const char*)T1l + tb + wo,        (char*)&bl[buf][0] + wid * 2048);        \
        glds16((const char*)T1l + tb + wo + 1024, (char*)&bl[buf][0] + wid * 2048 + 1024); }

    DMA3(0, 0);
    __syncthreads();
    #pragma unroll
    for (int kc = 0; kc < 4; ++kc) {
        const int cur = kc & 1;
        if (kc < 3) DMA3(kc + 1, cur ^ 1);
        {
            const int kk = (lane >> 4) * 8, rl = lane & 15;
            s8v Ah[4], Al[4], Bh[4], Bl[4];
            #pragma unroll
            for (int mf = 0; mf < 4; ++mf) {
                int us = SW32(wm + mf * 16 + rl, kk);
                Ah[mf] = *(const s8v*)&ah[cur][us];
                Al[mf] = *(const s8v*)&al[cur][us];
            }
            #pragma unroll
            for (int nf = 0; nf < 4; ++nf) {
                int us = SW32(wn + nf * 16 + rl, kk);
                Bh[nf] = *(const s8v*)&bh[cur][us];
                Bl[nf] = *(const s8v*)&bl[cur][us];
            }
            #pragma unroll
            for (int mf = 0; mf < 4; ++mf)
                #pragma unroll
                for (int nf = 0; nf < 4; ++nf)
                    acc[mf][nf] = __builtin_amdgcn_mfma_f32_16x16x32_bf16(Ah[mf], Bh[nf], acc[mf][nf], 0, 0, 0);
            #pragma unroll
            for (int mf = 0; mf < 4; ++mf)
                #pragma unroll
                for (int nf = 0; nf < 4; ++nf)
                    acc[mf][nf] = __builtin_amdgcn_mfma_f32_16x16x32_bf16(Al[mf], Bh[nf], acc[mf][nf], 0, 0, 0);
            #pragma unroll
            for (int mf = 0; mf < 4; ++mf)
                #pragma unroll
                for (int nf = 0; nf < 4; ++nf)
                    acc[mf][nf] = __builtin_amdgcn_mfma_f32_16x16x32_bf16(Ah[mf], Bl[nf], acc[mf][nf], 0, 0, 0);
        }
        __syncthreads();
    }
    #pragma unroll
    for (int mf = 0; mf < 4; ++mf) {
        int rr = rb * 128 + wm + mf * 16 + (lane >> 4) * 4;
        #pragma unroll
        for (int nf = 0; nf < 4; ++nf) {
            int c = sb * 128 + wn + nf * 16 + (lane & 15);
            #pragma unroll
            for (int r = 0; r < 4; ++r)
                __builtin_nontemporal_store(acc[mf][nf][r], &y[(size_t)(rr + r) * S_LEN + c]);
        }
    }
}

extern "C" void kernel_launch(void* const* d_in, const int* in_sizes, int n_in,
                              void* d_out, int out_size, void* d_ws, size_t ws_size,
                              hipStream_t stream) {
    const float* x      = (const float*)d_in[0];
    const float* w_real = (const float*)d_in[1];
    const float* w_imag = (const float*)d_in[2];
    float* y = (float*)d_out;

    const size_t TBL = (size_t)S_LEN * 128;       // 1M elems
    char* w0 = (char*)d_ws;
    short* T1h     = (short*)w0;                  // 2MB each half
    short* T1l     = T1h + TBL;
    _Float16* Bf   = (_Float16*)(T1l + TBL);      // 2MB, K1 B fragment image
    float* X       = (float*)(Bf + TBL);          // 2MB
    float* tab     = X + (size_t)4096 * 128;      // 32KB
    float* P       = tab + S_LEN;                 // 16MB (8 slices)
    // C2 overlaps P (disjoint lifetimes: P dead after ksum; C2 born at K2)
    short* C2h     = (short*)P;
    short* C2l     = C2h + TBL;
    const size_t TOTAL = (size_t)((char*)(P + 8 * (size_t)4096 * 128) - w0);  // ~24MB
    if (ws_size < TOTAL) {
        fprintf(stderr, "kernel_launch: ws too small (%zu < %zu bytes)\n", ws_size, TOTAL);
        return;
    }

    gen_master<<<S_LEN / 256, 256, 0, stream>>>(tab);
    gen_t1_img<<<(S_LEN * 128) / 256, 256, 0, stream>>>(tab, T1h, T1l);
    gen_b_frag<<<(S_LEN * 128) / 256, 256, 0, stream>>>(tab, Bf);
    dft_fwd_mfma<<<dim3(64, 8), 256, 0, stream>>>(x, Bf, P);
    ksum<<<512, 256, 0, stream>>>(P, X);
    mode_contract<<<dim3(NM, 4), 256, 0, stream>>>(X, w_real, w_imag, C2h, C2l);
    idft_mfma<<<dim3(S_LEN / 128, 4096 / 128), 256, 0, stream>>>(C2h, C2l, T1h, T1l, y);
}

// Round 14
// 130.458 us; speedup vs baseline: 1.0121x; 1.0121x over previous
//
#include <hip/hip_runtime.h>
#include <cstdio>

// B=32, Cin=128, S=8192, H=4, Hc=32, M=64, Cout=128
#define S_LEN 8192
#define NM 64

typedef short s8v __attribute__((ext_vector_type(8)));   // 8 bf16
typedef float f4  __attribute__((ext_vector_type(4)));
typedef _Float16 h8 __attribute__((ext_vector_type(8))); // 8 fp16

static __device__ inline unsigned short f2bf(float f) {  // RNE fp32->bf16
    unsigned int u = __builtin_bit_cast(unsigned int, f);
    u = (u + 0x7FFFu + ((u >> 16) & 1u)) >> 16;
    return (unsigned short)u;
}
static __device__ inline float bf2f(unsigned short h) {
    unsigned int u = ((unsigned int)h) << 16;
    return __builtin_bit_cast(float, u);
}

// C2/T1-image swizzle: [128 r][32 k] tile, XOR k-bits 3..4 with (r>>1)&3
#define SW32(r, k) (((r) * 32) + ((k) ^ ((((r) >> 1) & 3) << 3)))

static __device__ __forceinline__ void glds16(const void* g, void* l) {
    __builtin_amdgcn_global_load_lds(
        (const __attribute__((address_space(1))) unsigned int*)g,
        (__attribute__((address_space(3))) unsigned int*)l, 16, 0, 0);
}

// ---------------- master trig table: tab[p] = cos(2*pi*p/8192) ----------------
__global__ __launch_bounds__(256) void gen_master(float* __restrict__ tab) {
    int p = blockIdx.x * 256 + threadIdx.x;
    tab[p] = cosf((float)p * (6.28318530717958647692f / (float)S_LEN));
}

// T1 image (K3's B^T): (s,k) k=2m|2m+1; img[(sb*4+kc)*4096 + SW32(s&127,k&31)]
// -sin(theta_p) == cos(theta_{p+2048})
__global__ __launch_bounds__(256) void gen_t1_img(const float* __restrict__ tab,
                                                  short* __restrict__ Th,
                                                  short* __restrict__ Tl) {
    int tid = blockIdx.x * 256 + threadIdx.x;     // 1M
    int tile = tid >> 12;
    int sb = tile >> 2, kc = tile & 3;
    int us = tid & 4095;
    int ls = us >> 5, kx = us & 31;
    int lk = kx ^ (((ls >> 1) & 3) << 3);
    int s = sb * 128 + ls;
    int k = kc * 32 + lk;
    int m = k >> 1;
    int p = (m * s + ((k & 1) << 11)) & (S_LEN - 1);
    float v = tab[p];                             // k odd -> -sin; k=1 -> 0 (Im(DC) dropped)
    unsigned short h = f2bf(v);
    Th[tid] = (short)h;
    Tl[tid] = (short)f2bf(v - bf2f(h));
}

// Bfrag (K1's B in MFMA-fragment order, fp16): [kstep 256][nf 8][lane 64][8] = 2MB.
// lane=(kq<<4)|rl -> col=nf*16+rl, k=kstep*32+kq*8+e; val=(col&1)?-sin:cos(2pi m k/S).
__global__ __launch_bounds__(256) void gen_b_frag(const float* __restrict__ tab,
                                                  _Float16* __restrict__ Bf) {
    int tid = blockIdx.x * 256 + threadIdx.x;     // 1M
    int e = tid & 7;
    int lane = (tid >> 3) & 63;
    int nf = (tid >> 9) & 7;
    int kstep = tid >> 12;                        // 0..255
    int rl = lane & 15, kq = lane >> 4;
    int col = nf * 16 + rl;
    int m = col >> 1;
    int k = kstep * 32 + kq * 8 + e;
    int p = (m * k + ((col & 1) << 11)) & (S_LEN - 1);
    Bf[tid] = (_Float16)tab[p];
}

// ---------------- K1: waveprivate + explicit register double-buffer prefetch ----------------
// Grid (64,8) x 256 thr. Wave: 16 rows x 128 cols x K-chunk 1024 (32 steps of BK=32).
// NO LDS, NO barriers. Step s+1's 10 loads issued before step s's cvt+MFMA (named regs).
__global__ __launch_bounds__(256, 2) void dft_fwd_mfma(const float* __restrict__ x,
        const _Float16* __restrict__ Bf, float* __restrict__ P) {
    const int t = threadIdx.x;
    const int lane = t & 63, w = t >> 6;
    const int rl = lane & 15, kq = lane >> 4;
    const int mtile = blockIdx.x * 4 + w;         // 0..255
    const int ks = blockIdx.y;                    // 0..7
    const int row0 = mtile * 16;
    const size_t xbase = (size_t)(row0 + rl) * S_LEN + (size_t)ks * 1024 + (size_t)kq * 8;
    const char* bbase = (const char*)Bf + (size_t)ks * 32 * 8192 + (size_t)lane * 16;

    f4 acc[8];
    #pragma unroll
    for (int i = 0; i < 8; ++i) acc[i] = (f4){0.f, 0.f, 0.f, 0.f};

    f4 aE0, aE1, aO0, aO1;
    h8 bE[8], bO[8];

    #define LDA(SC, A0, A1) { A0 = *(const f4*)&x[xbase + (size_t)(SC) * 32];      \
                              A1 = *(const f4*)&x[xbase + (size_t)(SC) * 32 + 4]; }
    #define LDB(SC, BV) { _Pragma("unroll")                                        \
        for (int nf = 0; nf < 8; ++nf)                                             \
            BV[nf] = *(const h8*)(bbase + (size_t)(SC) * 8192 + (size_t)nf * 1024); }
    #define CMP(A0, A1, BV) { h8 Ah, Al;                                           \
        _Pragma("unroll")                                                          \
        for (int e = 0; e < 4; ++e) {                                              \
            float f = A0[e]; _Float16 hh = (_Float16)f;                            \
            Ah[e] = hh; Al[e] = (_Float16)(f - (float)hh);                         \
        }                                                                          \
        _Pragma("unroll")                                                          \
        for (int e = 0; e < 4; ++e) {                                              \
            float f = A1[e]; _Float16 hh = (_Float16)f;                            \
            Ah[4 + e] = hh; Al[4 + e] = (_Float16)(f - (float)hh);                 \
        }                                                                          \
        _Pragma("unroll")                                                          \
        for (int nf = 0; nf < 8; ++nf)                                             \
            acc[nf] = __builtin_amdgcn_mfma_f32_16x16x32_f16(Ah, BV[nf], acc[nf], 0, 0, 0); \
        _Pragma("unroll")                                                          \
        for (int nf = 0; nf < 8; ++nf)                                             \
            acc[nf] = __builtin_amdgcn_mfma_f32_16x16x32_f16(Al, BV[nf], acc[nf], 0, 0, 0); }

    // prologue: step 0 into E
    LDA(0, aE0, aE1) LDB(0, bE)
    #pragma unroll
    for (int s = 0; s < 32; s += 2) {
        // issue odd-step loads, then compute even step
        LDA(s + 1, aO0, aO1) LDB(s + 1, bO)
        __builtin_amdgcn_sched_barrier(0);
        CMP(aE0, aE1, bE)
        // issue next even-step loads, then compute odd step
        if (s + 2 < 32) { LDA(s + 2, aE0, aE1) LDB(s + 2, bE) }
        __builtin_amdgcn_sched_barrier(0);
        CMP(aO0, aO1, bO)
    }

    // D layout: col=lane&15, row=(lane>>4)*4+reg
    float* Pks = P + (size_t)ks * 524288;
    #pragma unroll
    for (int nf = 0; nf < 8; ++nf)
        #pragma unroll
        for (int r = 0; r < 4; ++r)
            Pks[(size_t)(row0 + kq * 4 + r) * 128 + nf * 16 + rl] = acc[nf][r];
}

// ---------------- ksum: X = sum of 8 P slices (coalesced) ----------------
__global__ __launch_bounds__(256) void ksum(const float* __restrict__ P,
                                            float* __restrict__ X) {
    int i = (blockIdx.x * 256 + threadIdx.x) * 4;
    f4 s = (f4){0.f, 0.f, 0.f, 0.f};
    #pragma unroll
    for (int ks = 0; ks < 8; ++ks)
        s += *(const f4*)&P[(size_t)ks * 524288 + i];
    *(f4*)&X[i] = s;
}

// ---------------- K2: mode contraction -> C2 image (pre-swizzled bf16 hi/lo) ----------------
__global__ __launch_bounds__(256) void mode_contract(const float* __restrict__ X,
        const float* __restrict__ w_real, const float* __restrict__ w_imag,
        short* __restrict__ C2h, short* __restrict__ C2l) {
    __shared__ float xr[32][128], xi[32][128];
    __shared__ float wr[128][32], wi[128][32];
    const int m = blockIdx.x, h = blockIdx.y, t = threadIdx.x;
    #pragma unroll
    for (int it = 0; it < 16; ++it) {
        int li = t + it * 256;       // 0..4095
        int b = li >> 7, i = li & 127;
        const float2 v = *(const float2*)&X[(size_t)(b * 128 + i) * 128 + 2 * m];
        xr[b][i] = v.x; xi[b][i] = v.y;
        int i2 = li >> 5, o = li & 31;
        size_t off = ((size_t)((h * 128 + i2) * 32 + o)) * NM + m;
        wr[i2][o] = w_real[off];
        wi[i2][o] = w_imag[off];
    }
    __syncthreads();
    const int o = t & 31;
    const int b0 = (t >> 5) * 4;
    float re[4] = {0.f, 0.f, 0.f, 0.f}, im[4] = {0.f, 0.f, 0.f, 0.f};
    for (int i = 0; i < 128; ++i) {
        float wrv = wr[i][o], wiv = wi[i][o];
        #pragma unroll
        for (int j = 0; j < 4; ++j) {
            float a = xr[b0 + j][i], c = xi[b0 + j][i];
            re[j] += a * wrv - c * wiv;
            im[j] += a * wiv + c * wrv;
        }
    }
    const float alpha = (m == 0) ? (1.0f / (float)S_LEN) : (2.0f / (float)S_LEN);
    const int kc = m >> 4;
    const int lk = (2 * m) & 31;
    #pragma unroll
    for (int j = 0; j < 4; ++j) {
        int row = (b0 + j) * 128 + h * 32 + o;
        float vr = alpha * re[j], vi = alpha * im[j];
        unsigned short hr = f2bf(vr), hi_ = f2bf(vi);
        float lr = vr - bf2f(hr), li_ = vi - bf2f(hi_);
        int rb = row >> 7, lr_ = row & 127;
        size_t ui = ((size_t)(rb * 4 + kc) * 4096 + SW32(lr_, lk)) >> 1;   // uint index
        ((unsigned int*)C2h)[ui] = ((unsigned int)hi_ << 16) | hr;
        ((unsigned int*)C2l)[ui] = ((unsigned int)f2bf(li_) << 16) | f2bf(lr);
    }
}

// ---------------- K3: y = C2[4096][128] * Basis[128][8192], dbuf DMA pipeline ----------------
__global__ __launch_bounds__(256, 2) void idft_mfma(const short* __restrict__ C2h,
        const short* __restrict__ C2l, const short* __restrict__ T1h,
        const short* __restrict__ T1l, float* __restrict__ y) {
    __shared__ short ah[2][4096], al[2][4096];
    __shared__ short bh[2][4096], bl[2][4096];
    const int t = threadIdx.x;
    const int lane = t & 63, wid = t >> 6;
    const int wm = (wid >> 1) * 64, wn = (wid & 1) * 64;
    const int sb = blockIdx.x;                    // col block (s), 0..63
    const int rb = blockIdx.y;                    // row block, 0..31
    f4 acc[4][4];
    #pragma unroll
    for (int i = 0; i < 4; ++i)
        #pragma unroll
        for (int j = 0; j < 4; ++j) acc[i][j] = (f4){0.f, 0.f, 0.f, 0.f};

    #define DMA3(kc, buf)  {                                                       \
        const size_t ta = (size_t)(rb * 4 + (kc)) * 8192;                          \
        const size_t tb = (size_t)(sb * 4 + (kc)) * 8192;                          \
        const int wo = wid * 2048 + lane * 16;                                     \
        glds16((const char*)C2h + ta + wo,        (char*)&ah[buf][0] + wid * 2048);        \
        glds16((const char*)C2h + ta + wo + 1024, (char*)&ah[buf][0] + wid * 2048 + 1024); \
        glds16((const char*)C2l + ta + wo,        (char*)&al[buf][0] + wid * 2048);        \
        glds16((const char*)C2l + ta + wo + 1024, (char*)&al[buf][0] + wid * 2048 + 1024); \
        glds16((const char*)T1h + tb + wo,        (char*)&bh[buf][0] + wid * 2048);        \
        glds16((const char*)T1h + tb + wo + 1024, (char*)&bh[buf][0] + wid * 2048 + 1024); \
        glds16((const char*)T1l + tb + wo,        (char*)&bl[buf][0] + wid * 2048);        \
        glds16((const char*)T1l + tb + wo + 1024, (char*)&bl[buf][0] + wid * 2048 + 1024); }

    DMA3(0, 0);
    __syncthreads();
    #pragma unroll
    for (int kc = 0; kc < 4; ++kc) {
        const int cur = kc & 1;
        if (kc < 3) DMA3(kc + 1, cur ^ 1);
        {
            const int kk = (lane >> 4) * 8, rl = lane & 15;
            s8v Ah[4], Al[4], Bh[4], Bl[4];
            #pragma unroll
            for (int mf = 0; mf < 4; ++mf) {
                int us = SW32(wm + mf * 16 + rl, kk);
                Ah[mf] = *(const s8v*)&ah[cur][us];
                Al[mf] = *(const s8v*)&al[cur][us];
            }
            #pragma unroll
            for (int nf = 0; nf < 4; ++nf) {
                int us = SW32(wn + nf * 16 + rl, kk);
                Bh[nf] = *(const s8v*)&bh[cur][us];
                Bl[nf] = *(const s8v*)&bl[cur][us];
            }
            #pragma unroll
            for (int mf = 0; mf < 4; ++mf)
                #pragma unroll
                for (int nf = 0; nf < 4; ++nf)
                    acc[mf][nf] = __builtin_amdgcn_mfma_f32_16x16x32_bf16(Ah[mf], Bh[nf], acc[mf][nf], 0, 0, 0);
            #pragma unroll
            for (int mf = 0; mf < 4; ++mf)
                #pragma unroll
                for (int nf = 0; nf < 4; ++nf)
                    acc[mf][nf] = __builtin_amdgcn_mfma_f32_16x16x32_bf16(Al[mf], Bh[nf], acc[mf][nf], 0, 0, 0);
            #pragma unroll
            for (int mf = 0; mf < 4; ++mf)
                #pragma unroll
                for (int nf = 0; nf < 4; ++nf)
                    acc[mf][nf] = __builtin_amdgcn_mfma_f32_16x16x32_bf16(Ah[mf], Bl[nf], acc[mf][nf], 0, 0, 0);
        }
        __syncthreads();
    }
    #pragma unroll
    for (int mf = 0; mf < 4; ++mf) {
        int rr = rb * 128 + wm + mf * 16 + (lane >> 4) * 4;
        #pragma unroll
        for (int nf = 0; nf < 4; ++nf) {
            int c = sb * 128 + wn + nf * 16 + (lane & 15);
            #pragma unroll
            for (int r = 0; r < 4; ++r)
                __builtin_nontemporal_store(acc[mf][nf][r], &y[(size_t)(rr + r) * S_LEN + c]);
        }
    }
}

extern "C" void kernel_launch(void* const* d_in, const int* in_sizes, int n_in,
                              void* d_out, int out_size, void* d_ws, size_t ws_size,
                              hipStream_t stream) {
    const float* x      = (const float*)d_in[0];
    const float* w_real = (const float*)d_in[1];
    const float* w_imag = (const float*)d_in[2];
    float* y = (float*)d_out;

    const size_t TBL = (size_t)S_LEN * 128;       // 1M elems
    char* w0 = (char*)d_ws;
    short* T1h     = (short*)w0;                  // 2MB each half
    short* T1l     = T1h + TBL;
    _Float16* Bf   = (_Float16*)(T1l + TBL);      // 2MB, K1 B fragment image
    float* X       = (float*)(Bf + TBL);          // 2MB
    float* tab     = X + (size_t)4096 * 128;      // 32KB
    float* P       = tab + S_LEN;                 // 16MB (8 slices)
    // C2 overlaps P (disjoint lifetimes: P dead after ksum; C2 born at K2)
    short* C2h     = (short*)P;
    short* C2l     = C2h + TBL;
    const size_t TOTAL = (size_t)((char*)(P + 8 * (size_t)4096 * 128) - w0);  // ~24MB
    if (ws_size < TOTAL) {
        fprintf(stderr, "kernel_launch: ws too small (%zu < %zu bytes)\n", ws_size, TOTAL);
        return;
    }

    gen_master<<<S_LEN / 256, 256, 0, stream>>>(tab);
    gen_t1_img<<<(S_LEN * 128) / 256, 256, 0, stream>>>(tab, T1h, T1l);
    gen_b_frag<<<(S_LEN * 128) / 256, 256, 0, stream>>>(tab, Bf);
    dft_fwd_mfma<<<dim3(64, 8), 256, 0, stream>>>(x, Bf, P);
    ksum<<<512, 256, 0, stream>>>(P, X);
    mode_contract<<<dim3(NM, 4), 256, 0, stream>>>(X, w_real, w_imag, C2h, C2l);
    idft_mfma<<<dim3(S_LEN / 128, 4096 / 128), 256, 0, stream>>>(C2h, C2l, T1h, T1l, y);
}

// Round 15
// 124.074 us; speedup vs baseline: 1.0641x; 1.0515x over previous
//
#include <hip/hip_runtime.h>
#include <cstdio>

// B=32, Cin=128, S=8192, H=4, Hc=32, M=64, Cout=128
#define S_LEN 8192
#define NM 64

typedef short s8v __attribute__((ext_vector_type(8)));   // 8 bf16
typedef float f4  __attribute__((ext_vector_type(4)));
typedef _Float16 h8 __attribute__((ext_vector_type(8))); // 8 fp16
typedef _Float16 h4 __attribute__((ext_vector_type(4)));

static __device__ inline unsigned short f2bf(float f) {  // RNE fp32->bf16
    unsigned int u = __builtin_bit_cast(unsigned int, f);
    u = (u + 0x7FFFu + ((u >> 16) & 1u)) >> 16;
    return (unsigned short)u;
}
static __device__ inline float bf2f(unsigned short h) {
    unsigned int u = ((unsigned int)h) << 16;
    return __builtin_bit_cast(float, u);
}

// C2/T1-image swizzle: [128 r][32 k] tile, XOR k-bits 3..4 with (r>>1)&3
#define SW32(r, k) (((r) * 32) + ((k) ^ ((((r) >> 1) & 3) << 3)))

static __device__ __forceinline__ void glds16(const void* g, void* l) {
    __builtin_amdgcn_global_load_lds(
        (const __attribute__((address_space(1))) unsigned int*)g,
        (__attribute__((address_space(3))) unsigned int*)l, 16, 0, 0);
}

// ---------------- master trig table: tab[p] = cos(2*pi*p/8192) ----------------
__global__ __launch_bounds__(256) void gen_master(float* __restrict__ tab) {
    int p = blockIdx.x * 256 + threadIdx.x;
    tab[p] = cosf((float)p * (6.28318530717958647692f / (float)S_LEN));
}

// T1 image (K3's B^T): (s,k) k=2m|2m+1; img[(sb*4+kc)*4096 + SW32(s&127,k&31)]
__global__ __launch_bounds__(256) void gen_t1_img(const float* __restrict__ tab,
                                                  short* __restrict__ Th,
                                                  short* __restrict__ Tl) {
    int tid = blockIdx.x * 256 + threadIdx.x;     // 1M
    int tile = tid >> 12;
    int sb = tile >> 2, kc = tile & 3;
    int us = tid & 4095;
    int ls = us >> 5, kx = us & 31;
    int lk = kx ^ (((ls >> 1) & 3) << 3);
    int s = sb * 128 + ls;
    int k = kc * 32 + lk;
    int m = k >> 1;
    int p = (m * s + ((k & 1) << 11)) & (S_LEN - 1);
    float v = tab[p];                             // k odd -> -sin; k=1 -> 0 (Im(DC) dropped)
    unsigned short h = f2bf(v);
    Th[tid] = (short)h;
    Tl[tid] = (short)f2bf(v - bf2f(h));
}

// Bimg (K1's B LDS image): 128 tiles (k-steps of 64) x [128 c][64 k] fp16 = 16KB/tile.
// us(c,k) = c*64 + (((k>>3) ^ (c&7))<<3) + (k&7). val = (c&1) ? -sin(2pi m kg/S) : cos.
__global__ __launch_bounds__(256) void gen_b_img(const float* __restrict__ tab,
                                                 _Float16* __restrict__ Bimg) {
    int tid = blockIdx.x * 256 + threadIdx.x;     // 1M fp16
    int tk = tid >> 13;
    int us = tid & 8191;
    int c = us >> 6;
    int wl = us & 63;
    int slot = wl >> 3, e = wl & 7;
    int k = ((slot ^ (c & 7)) << 3) | e;          // invert swizzle
    int kg = tk * 64 + k;
    int m = c >> 1;
    int p = (m * kg + ((c & 1) << 11)) & (S_LEN - 1);
    Bimg[tid] = (_Float16)tab[p];
}

// ---------------- K1: P[ks] = x * B1 ; BM=32 BN=128 BK=64; A fp16 SINGLE ----------------
// 1024 blocks (128 rb x 8 ks) x 512 thr (8 waves, 2M x 4N of 16x32 tiles).
// launch_bounds(512,6) -> 3 blocks/CU (24 waves/CU). LDS 40KB. Same R12 pipeline
// (A dist-3, B dist-2 reg-staged, lgkm-only barriers; A-loads fly across barriers).
__global__ __launch_bounds__(512, 6) void dft_fwd_mfma(const float* __restrict__ x,
        const _Float16* __restrict__ Bimg, float* __restrict__ P) {
    __shared__ _Float16 ab[2][2048];              // A [32r][64k] fp16, 4KB/buf
    __shared__ _Float16 bb[2][8192];              // B [128c][64k], 16KB/buf
    const int t = threadIdx.x;
    const int lane = t & 63, w = t >> 6;
    const int rl = lane & 15, kq = lane >> 4;
    const int wr = w >> 2, wc = w & 3;            // 2M x 4N wave grid
    const int row0 = blockIdx.x * 32;
    const int ks = blockIdx.y;                    // 0..7
    const int rA = t >> 4, kfA = (t & 15) * 4;    // A stage: row rA, 4 floats at kfA
    const size_t xrow = (size_t)(row0 + rA) * S_LEN + (size_t)ks * 1024 + kfA;
    const int usA = rA * 64 + ((((kfA >> 3) ^ rA) & 7) << 3) + (kfA & 7);
    const size_t bby = (size_t)ks * 16 * 16384 + (size_t)t * 32;

    f4 acc[2];
    acc[0] = (f4){0.f, 0.f, 0.f, 0.f};
    acc[1] = (f4){0.f, 0.f, 0.f, 0.f};
    f4 aP[3];
    h8 bP[2][2];

    #define LA_(SC, A0) { A0 = *(const f4*)&x[xrow + (size_t)(SC) * 64]; }
    #define LB_(SC, B0, B1) { const char* g = (const char*)Bimg + bby +            \
                                  (size_t)(SC) * 16384;                            \
                              B0 = *(const h8*)g; B1 = *(const h8*)(g + 16); }
    #define CV_(A0, NXT) { h4 hv;                                                  \
        _Pragma("unroll")                                                          \
        for (int e = 0; e < 4; ++e) hv[e] = (_Float16)A0[e];                       \
        *(h4*)&ab[NXT][usA] = hv; }
    #define WB_(B0, B1, NXT) { *(h8*)&bb[NXT][t * 16] = B0;                        \
                               *(h8*)&bb[NXT][t * 16 + 8] = B1; }
    #define MM_(CUR) { _Pragma("unroll")                                           \
        for (int ksl = 0; ksl < 2; ++ksl) {                                        \
            const int slot = ksl * 4 + kq;                                         \
            const int r = wr * 16 + rl;                                            \
            h8 Av = *(const h8*)&ab[CUR][r * 64 + ((slot ^ (r & 7)) << 3)];        \
            _Pragma("unroll")                                                      \
            for (int nf = 0; nf < 2; ++nf) {                                       \
                const int c = wc * 32 + nf * 16 + rl;                              \
                h8 Bv = *(const h8*)&bb[CUR][c * 64 + ((slot ^ (c & 7)) << 3)];    \
                acc[nf] = __builtin_amdgcn_mfma_f32_16x16x32_f16(Av, Bv, acc[nf], 0, 0, 0); \
            } } }
    #define BAR_ __builtin_amdgcn_sched_barrier(0);                                \
        asm volatile("s_waitcnt lgkmcnt(0)" ::: "memory");                         \
        __builtin_amdgcn_sched_barrier(0);                                         \
        __builtin_amdgcn_s_barrier();                                              \
        __builtin_amdgcn_sched_barrier(0);

    // prologue: chunk0 staged to buf0; chunks 1,2 in aP[1],aP[2]; chunk1-B in bP[1]
    {
        f4 t0a; h8 tb0a, tb0b;
        LA_(0, t0a) LB_(0, tb0a, tb0b)
        LA_(1, aP[1]) LA_(2, aP[2])
        LB_(1, bP[1][0], bP[1][1])
        __builtin_amdgcn_sched_barrier(0);
        CV_(t0a, 0) WB_(tb0a, tb0b, 0)
        BAR_
    }
    // steps 0..15; chunk c: A loaded at step c-3 into aP[c%3], B at c-2 into bP[c&1];
    // staged (CV/WB) at step c-1 into buf[c&1]; consumed (MM) at step c.
    #pragma unroll
    for (int s = 0; s < 16; ++s) {
        if (s + 3 <= 15) LA_(s + 3, aP[(s + 3) % 3])
        if (s + 2 <= 15) LB_(s + 2, bP[(s + 2) & 1][0], bP[(s + 2) & 1][1])
        __builtin_amdgcn_sched_barrier(0);
        if (s + 1 <= 15) { CV_(aP[(s + 1) % 3], (s + 1) & 1)
                           WB_(bP[(s + 1) & 1][0], bP[(s + 1) & 1][1], (s + 1) & 1) }
        MM_(s & 1)
        if (s < 15) { BAR_ }
    }

    // D layout: col=lane&15, row=(lane>>4)*4+reg
    float* Pks = P + (size_t)ks * 524288;
    #pragma unroll
    for (int nf = 0; nf < 2; ++nf)
        #pragma unroll
        for (int r = 0; r < 4; ++r)
            Pks[(size_t)(row0 + wr * 16 + kq * 4 + r) * 128
                + wc * 32 + nf * 16 + rl] = acc[nf][r];
}

// ---------------- ksum: X = sum of 8 P slices (coalesced) ----------------
__global__ __launch_bounds__(256) void ksum(const float* __restrict__ P,
                                            float* __restrict__ X) {
    int i = (blockIdx.x * 256 + threadIdx.x) * 4;
    f4 s = (f4){0.f, 0.f, 0.f, 0.f};
    #pragma unroll
    for (int ks = 0; ks < 8; ++ks)
        s += *(const f4*)&P[(size_t)ks * 524288 + i];
    *(f4*)&X[i] = s;
}

// ---------------- K2: mode contraction -> C2 image (pre-swizzled bf16 hi/lo) ----------------
__global__ __launch_bounds__(256) void mode_contract(const float* __restrict__ X,
        const float* __restrict__ w_real, const float* __restrict__ w_imag,
        short* __restrict__ C2h, short* __restrict__ C2l) {
    __shared__ float xr[32][128], xi[32][128];
    __shared__ float wr[128][32], wi[128][32];
    const int m = blockIdx.x, h = blockIdx.y, t = threadIdx.x;
    #pragma unroll
    for (int it = 0; it < 16; ++it) {
        int li = t + it * 256;       // 0..4095
        int b = li >> 7, i = li & 127;
        const float2 v = *(const float2*)&X[(size_t)(b * 128 + i) * 128 + 2 * m];
        xr[b][i] = v.x; xi[b][i] = v.y;
        int i2 = li >> 5, o = li & 31;
        size_t off = ((size_t)((h * 128 + i2) * 32 + o)) * NM + m;
        wr[i2][o] = w_real[off];
        wi[i2][o] = w_imag[off];
    }
    __syncthreads();
    const int o = t & 31;
    const int b0 = (t >> 5) * 4;
    float re[4] = {0.f, 0.f, 0.f, 0.f}, im[4] = {0.f, 0.f, 0.f, 0.f};
    for (int i = 0; i < 128; ++i) {
        float wrv = wr[i][o], wiv = wi[i][o];
        #pragma unroll
        for (int j = 0; j < 4; ++j) {
            float a = xr[b0 + j][i], c = xi[b0 + j][i];
            re[j] += a * wrv - c * wiv;
            im[j] += a * wiv + c * wrv;
        }
    }
    const float alpha = (m == 0) ? (1.0f / (float)S_LEN) : (2.0f / (float)S_LEN);
    const int kc = m >> 4;
    const int lk = (2 * m) & 31;
    #pragma unroll
    for (int j = 0; j < 4; ++j) {
        int row = (b0 + j) * 128 + h * 32 + o;
        float vr = alpha * re[j], vi = alpha * im[j];
        unsigned short hr = f2bf(vr), hi_ = f2bf(vi);
        float lr = vr - bf2f(hr), li_ = vi - bf2f(hi_);
        int rb = row >> 7, lr_ = row & 127;
        size_t ui = ((size_t)(rb * 4 + kc) * 4096 + SW32(lr_, lk)) >> 1;   // uint index
        ((unsigned int*)C2h)[ui] = ((unsigned int)hi_ << 16) | hr;
        ((unsigned int*)C2l)[ui] = ((unsigned int)f2bf(li_) << 16) | f2bf(lr);
    }
}

// ---------------- K3: y = C2[4096][128] * Basis[128][8192], dbuf DMA pipeline ----------------
__global__ __launch_bounds__(256, 2) void idft_mfma(const short* __restrict__ C2h,
        const short* __restrict__ C2l, const short* __restrict__ T1h,
        const short* __restrict__ T1l, float* __restrict__ y) {
    __shared__ short ah[2][4096], al[2][4096];
    __shared__ short bh[2][4096], bl[2][4096];
    const int t = threadIdx.x;
    const int lane = t & 63, wid = t >> 6;
    const int wm = (wid >> 1) * 64, wn = (wid & 1) * 64;
    const int sb = blockIdx.x;                    // col block (s), 0..63
    const int rb = blockIdx.y;                    // row block, 0..31
    f4 acc[4][4];
    #pragma unroll
    for (int i = 0; i < 4; ++i)
        #pragma unroll
        for (int j = 0; j < 4; ++j) acc[i][j] = (f4){0.f, 0.f, 0.f, 0.f};

    #define DMA3(kc, buf)  {                                                       \
        const size_t ta = (size_t)(rb * 4 + (kc)) * 8192;                          \
        const size_t tb = (size_t)(sb * 4 + (kc)) * 8192;                          \
        const int wo = wid * 2048 + lane * 16;                                     \
        glds16((const char*)C2h + ta + wo,        (char*)&ah[buf][0] + wid * 2048);        \
        glds16((const char*)C2h + ta + wo + 1024, (char*)&ah[buf][0] + wid * 2048 + 1024); \
        glds16((const char*)C2l + ta + wo,        (char*)&al[buf][0] + wid * 2048);        \
        glds16((const char*)C2l + ta + wo + 1024, (char*)&al[buf][0] + wid * 2048 + 1024); \
        glds16((const char*)T1h + tb + wo,        (char*)&bh[buf][0] + wid * 2048);        \
        glds16((const char*)T1h + tb + wo + 1024, (char*)&bh[buf][0] + wid * 2048 + 1024); \
        glds16((const char*)T1l + tb + wo,        (char*)&bl[buf][0] + wid * 2048);        \
        glds16((const char*)T1l + tb + wo + 1024, (char*)&bl[buf][0] + wid * 2048 + 1024); }

    DMA3(0, 0);
    __syncthreads();
    #pragma unroll
    for (int kc = 0; kc < 4; ++kc) {
        const int cur = kc & 1;
        if (kc < 3) DMA3(kc + 1, cur ^ 1);
        {
            const int kk = (lane >> 4) * 8, rl = lane & 15;
            s8v Ah[4], Al[4], Bh[4], Bl[4];
            #pragma unroll
            for (int mf = 0; mf < 4; ++mf) {
                int us = SW32(wm + mf * 16 + rl, kk);
                Ah[mf] = *(const s8v*)&ah[cur][us];
                Al[mf] = *(const s8v*)&al[cur][us];
            }
            #pragma unroll
            for (int nf = 0; nf < 4; ++nf) {
                int us = SW32(wn + nf * 16 + rl, kk);
                Bh[nf] = *(const s8v*)&bh[cur][us];
                Bl[nf] = *(const s8v*)&bl[cur][us];
            }
            #pragma unroll
            for (int mf = 0; mf < 4; ++mf)
                #pragma unroll
                for (int nf = 0; nf < 4; ++nf)
                    acc[mf][nf] = __builtin_amdgcn_mfma_f32_16x16x32_bf16(Ah[mf], Bh[nf], acc[mf][nf], 0, 0, 0);
            #pragma unroll
            for (int mf = 0; mf < 4; ++mf)
                #pragma unroll
                for (int nf = 0; nf < 4; ++nf)
                    acc[mf][nf] = __builtin_amdgcn_mfma_f32_16x16x32_bf16(Al[mf], Bh[nf], acc[mf][nf], 0, 0, 0);
            #pragma unroll
            for (int mf = 0; mf < 4; ++mf)
                #pragma unroll
                for (int nf = 0; nf < 4; ++nf)
                    acc[mf][nf] = __builtin_amdgcn_mfma_f32_16x16x32_bf16(Ah[mf], Bl[nf], acc[mf][nf], 0, 0, 0);
        }
        __syncthreads();
    }
    #pragma unroll
    for (int mf = 0; mf < 4; ++mf) {
        int rr = rb * 128 + wm + mf * 16 + (lane >> 4) * 4;
        #pragma unroll
        for (int nf = 0; nf < 4; ++nf) {
            int c = sb * 128 + wn + nf * 16 + (lane & 15);
            #pragma unroll
            for (int r = 0; r < 4; ++r)
                __builtin_nontemporal_store(acc[mf][nf][r], &y[(size_t)(rr + r) * S_LEN + c]);
        }
    }
}

extern "C" void kernel_launch(void* const* d_in, const int* in_sizes, int n_in,
                              void* d_out, int out_size, void* d_ws, size_t ws_size,
                              hipStream_t stream) {
    const float* x      = (const float*)d_in[0];
    const float* w_real = (const float*)d_in[1];
    const float* w_imag = (const float*)d_in[2];
    float* y = (float*)d_out;

    const size_t TBL = (size_t)S_LEN * 128;       // 1M elems
    char* w0 = (char*)d_ws;
    short* T1h     = (short*)w0;                  // 2MB each half
    short* T1l     = T1h + TBL;
    _Float16* Bimg = (_Float16*)(T1l + TBL);      // 2MB, K1 B LDS image
    float* X       = (float*)(Bimg + TBL);        // 2MB
    float* tab     = X + (size_t)4096 * 128;      // 32KB
    float* P       = tab + S_LEN;                 // 16MB (8 slices)
    // C2 overlaps P (disjoint lifetimes: P dead after ksum; C2 born at K2)
    short* C2h     = (short*)P;
    short* C2l     = C2h + TBL;
    const size_t TOTAL = (size_t)((char*)(P + 8 * (size_t)4096 * 128) - w0);  // ~24MB
    if (ws_size < TOTAL) {
        fprintf(stderr, "kernel_launch: ws too small (%zu < %zu bytes)\n", ws_size, TOTAL);
        return;
    }

    gen_master<<<S_LEN / 256, 256, 0, stream>>>(tab);
    gen_t1_img<<<(S_LEN * 128) / 256, 256, 0, stream>>>(tab, T1h, T1l);
    gen_b_img<<<(S_LEN * 128) / 256, 256, 0, stream>>>(tab, Bimg);
    dft_fwd_mfma<<<dim3(128, 8), 512, 0, stream>>>(x, Bimg, P);
    ksum<<<512, 256, 0, stream>>>(P, X);
    mode_contract<<<dim3(NM, 4), 256, 0, stream>>>(X, w_real, w_imag, C2h, C2l);
    idft_mfma<<<dim3(S_LEN / 128, 4096 / 128), 256, 0, stream>>>(C2h, C2l, T1h, T1l, y);
}

// Round 16
// 122.932 us; speedup vs baseline: 1.0740x; 1.0093x over previous
//
#include <hip/hip_runtime.h>
#include <cstdio>

// B=32, Cin=128, S=8192, H=4, Hc=32, M=64, Cout=128
#define S_LEN 8192
#define NM 64

typedef short s8v __attribute__((ext_vector_type(8)));   // 8 bf16
typedef float f4  __attribute__((ext_vector_type(4)));
typedef _Float16 h8 __attribute__((ext_vector_type(8))); // 8 fp16

static __device__ inline unsigned short f2bf(float f) {  // RNE fp32->bf16
    unsigned int u = __builtin_bit_cast(unsigned int, f);
    u = (u + 0x7FFFu + ((u >> 16) & 1u)) >> 16;
    return (unsigned short)u;
}
static __device__ inline float bf2f(unsigned short h) {
    unsigned int u = ((unsigned int)h) << 16;
    return __builtin_bit_cast(float, u);
}

// C2-image swizzle: [128 r][32 k] tile, XOR k-bits 3..4 with (r>>1)&3
#define SW32(r, k) (((r) * 32) + ((k) ^ ((((r) >> 1) & 3) << 3)))

static __device__ __forceinline__ void glds16(const void* g, void* l) {
    __builtin_amdgcn_global_load_lds(
        (const __attribute__((address_space(1))) unsigned int*)g,
        (__attribute__((address_space(3))) unsigned int*)l, 16, 0, 0);
}

// ---------------- master trig table: tab[p] = cos(2*pi*p/8192) ----------------
__global__ __launch_bounds__(256) void gen_master(float* __restrict__ tab) {
    int p = blockIdx.x * 256 + threadIdx.x;
    tab[p] = cosf((float)p * (6.28318530717958647692f / (float)S_LEN));
}

// ---------------- fused table gen: T1frag (K3 B, fragment order) + Bimg (K1 B, LDS-image) ----
// T1frag: per tile (sb*4+kc): ushort idx = tile*4096 + c*32 + (kq*8+e); k=kc*32+kq*8+e
//         (k=2m|2m+1), s=sb*128+c; val = k odd ? -sin(2pi m s/S) : cos (k=1 -> 0: Im(DC) drop)
// Bimg:   128 tiles (ksteps of 64) x [128 c][64 k] fp16; us(c,k)=c*64+(((k>>3)^(c&7))<<3)+(k&7)
__global__ __launch_bounds__(256) void gen_tables(const float* __restrict__ tab,
                                                  short* __restrict__ T1fH,
                                                  short* __restrict__ T1fL,
                                                  _Float16* __restrict__ Bimg) {
    int tid = blockIdx.x * 256 + threadIdx.x;     // 1M
    {   // T1frag element
        int tile = tid >> 12;
        int sb = tile >> 2, kc = tile & 3;
        int uw = tid & 4095;
        int c = uw >> 5, rest = uw & 31;
        int k = kc * 32 + rest;
        int s = sb * 128 + c;
        int m = k >> 1;
        int p = (m * s + ((k & 1) << 11)) & (S_LEN - 1);
        float v = tab[p];
        unsigned short h = f2bf(v);
        T1fH[tid] = (short)h;
        T1fL[tid] = (short)f2bf(v - bf2f(h));
    }
    {   // Bimg element
        int tk = tid >> 13;
        int us = tid & 8191;
        int c = us >> 6;
        int wl = us & 63;
        int slot = wl >> 3, e = wl & 7;
        int k = ((slot ^ (c & 7)) << 3) | e;      // invert swizzle
        int kg = tk * 64 + k;
        int m = c >> 1;
        int p = (m * kg + ((c & 1) << 11)) & (S_LEN - 1);
        Bimg[tid] = (_Float16)tab[p];
    }
}

// ---------------- K1: P[ks] = x * B1 ; BM=64 BN=128 BK=64; A dist-3, B dist-2 (R12) --------
__global__ __launch_bounds__(512, 4) void dft_fwd_mfma(const float* __restrict__ x,
        const _Float16* __restrict__ Bimg, float* __restrict__ P) {
    __shared__ _Float16 abh[2][4096], abl[2][4096];   // A hi/lo [64r][64k], 8KB/buf
    __shared__ _Float16 bb[2][8192];                  // B [128c][64k], 16KB/buf
    const int t = threadIdx.x;
    const int lane = t & 63, w = t >> 6;
    const int rl = lane & 15, kq = lane >> 4;
    const int wr = w >> 2, wc = w & 3;
    const int row0 = blockIdx.x * 64;
    const int ks = blockIdx.y;                        // 0..7
    const int rA = t >> 3, sA = t & 7;
    const size_t xrow = (size_t)(row0 + rA) * S_LEN + (size_t)ks * 1024 + (size_t)sA * 8;
    const int usA = rA * 64 + ((sA ^ (rA & 7)) << 3);
    const size_t bby = (size_t)ks * 16 * 16384 + (size_t)t * 32;

    f4 acc[2][2];
    #pragma unroll
    for (int i = 0; i < 2; ++i)
        #pragma unroll
        for (int j = 0; j < 2; ++j) acc[i][j] = (f4){0.f, 0.f, 0.f, 0.f};

    f4 aP[3][2];
    h8 bP[2][2];

    #define LA_(SC, A0, A1) { A0 = *(const f4*)&x[xrow + (size_t)(SC) * 64];       \
                              A1 = *(const f4*)&x[xrow + (size_t)(SC) * 64 + 4]; }
    #define LB_(SC, B0, B1) { const char* g = (const char*)Bimg + bby +            \
                                  (size_t)(SC) * 16384;                            \
                              B0 = *(const h8*)g; B1 = *(const h8*)(g + 16); }
    #define CV_(A0, A1, NXT) { h8 hv, lv;                                          \
        _Pragma("unroll")                                                          \
        for (int e = 0; e < 4; ++e) {                                              \
            float f = A0[e]; _Float16 hh = (_Float16)f;                            \
            hv[e] = hh; lv[e] = (_Float16)(f - (float)hh);                         \
        }                                                                          \
        _Pragma("unroll")                                                          \
        for (int e = 0; e < 4; ++e) {                                              \
            float f = A1[e]; _Float16 hh = (_Float16)f;                            \
            hv[4 + e] = hh; lv[4 + e] = (_Float16)(f - (float)hh);                 \
        }                                                                          \
        *(h8*)&abh[NXT][usA] = hv;                                                 \
        *(h8*)&abl[NXT][usA] = lv; }
    #define WB_(B0, B1, NXT) { *(h8*)&bb[NXT][t * 16] = B0;                        \
                               *(h8*)&bb[NXT][t * 16 + 8] = B1; }
    #define MM_(CUR) { _Pragma("unroll")                                           \
        for (int ksl = 0; ksl < 2; ++ksl) {                                        \
            const int sb_ = ksl * 4 + kq;                                          \
            h8 Ah0, Al0, Ah1, Al1, Bv0, Bv1;                                       \
            { int r = wr * 32 + rl;      int u = r * 64 + ((sb_ ^ (r & 7)) << 3);  \
              Ah0 = *(const h8*)&abh[CUR][u]; Al0 = *(const h8*)&abl[CUR][u]; }    \
            { int r = wr * 32 + 16 + rl; int u = r * 64 + ((sb_ ^ (r & 7)) << 3);  \
              Ah1 = *(const h8*)&abh[CUR][u]; Al1 = *(const h8*)&abl[CUR][u]; }    \
            { int c = wc * 32 + rl;      int u = c * 64 + ((sb_ ^ (c & 7)) << 3);  \
              Bv0 = *(const h8*)&bb[CUR][u]; }                                     \
            { int c = wc * 32 + 16 + rl; int u = c * 64 + ((sb_ ^ (c & 7)) << 3);  \
              Bv1 = *(const h8*)&bb[CUR][u]; }                                     \
            acc[0][0] = __builtin_amdgcn_mfma_f32_16x16x32_f16(Ah0, Bv0, acc[0][0], 0, 0, 0); \
            acc[0][1] = __builtin_amdgcn_mfma_f32_16x16x32_f16(Ah0, Bv1, acc[0][1], 0, 0, 0); \
            acc[1][0] = __builtin_amdgcn_mfma_f32_16x16x32_f16(Ah1, Bv0, acc[1][0], 0, 0, 0); \
            acc[1][1] = __builtin_amdgcn_mfma_f32_16x16x32_f16(Ah1, Bv1, acc[1][1], 0, 0, 0); \
            acc[0][0] = __builtin_amdgcn_mfma_f32_16x16x32_f16(Al0, Bv0, acc[0][0], 0, 0, 0); \
            acc[0][1] = __builtin_amdgcn_mfma_f32_16x16x32_f16(Al0, Bv1, acc[0][1], 0, 0, 0); \
            acc[1][0] = __builtin_amdgcn_mfma_f32_16x16x32_f16(Al1, Bv0, acc[1][0], 0, 0, 0); \
            acc[1][1] = __builtin_amdgcn_mfma_f32_16x16x32_f16(Al1, Bv1, acc[1][1], 0, 0, 0); \
        } }
    #define BAR_ __builtin_amdgcn_sched_barrier(0);                                \
        asm volatile("s_waitcnt lgkmcnt(0)" ::: "memory");                         \
        __builtin_amdgcn_sched_barrier(0);                                         \
        __builtin_amdgcn_s_barrier();                                              \
        __builtin_amdgcn_sched_barrier(0);

    {
        f4 t0a, t0b; h8 tb0a, tb0b;
        LA_(0, t0a, t0b) LB_(0, tb0a, tb0b)
        LA_(1, aP[1][0], aP[1][1]) LA_(2, aP[2][0], aP[2][1])
        LB_(1, bP[1][0], bP[1][1])
        __builtin_amdgcn_sched_barrier(0);
        CV_(t0a, t0b, 0) WB_(tb0a, tb0b, 0)
        BAR_
    }
    #pragma unroll
    for (int s = 0; s < 16; ++s) {
        if (s + 3 <= 15) LA_(s + 3, aP[(s + 3) % 3][0], aP[(s + 3) % 3][1])
        if (s + 2 <= 15) LB_(s + 2, bP[(s + 2) & 1][0], bP[(s + 2) & 1][1])
        __builtin_amdgcn_sched_barrier(0);
        if (s + 1 <= 15) { CV_(aP[(s + 1) % 3][0], aP[(s + 1) % 3][1], (s + 1) & 1)
                           WB_(bP[(s + 1) & 1][0], bP[(s + 1) & 1][1], (s + 1) & 1) }
        MM_(s & 1)
        if (s < 15) { BAR_ }
    }

    // D layout: col=lane&15, row=(lane>>4)*4+reg
    float* Pks = P + (size_t)ks * 524288;
    #pragma unroll
    for (int mf = 0; mf < 2; ++mf)
        #pragma unroll
        for (int nf = 0; nf < 2; ++nf)
            #pragma unroll
            for (int r = 0; r < 4; ++r)
                Pks[(size_t)(row0 + wr * 32 + mf * 16 + kq * 4 + r) * 128
                    + wc * 32 + nf * 16 + rl] = acc[mf][nf][r];
}

// ---------------- ksum: X = sum of 8 P slices (coalesced) ----------------
__global__ __launch_bounds__(256) void ksum(const float* __restrict__ P,
                                            float* __restrict__ X) {
    int i = (blockIdx.x * 256 + threadIdx.x) * 4;
    f4 s = (f4){0.f, 0.f, 0.f, 0.f};
    #pragma unroll
    for (int ks = 0; ks < 8; ++ks)
        s += *(const f4*)&P[(size_t)ks * 524288 + i];
    *(f4*)&X[i] = s;
}

// ---------------- K2: mode contraction -> C2 image (pre-swizzled bf16 hi/lo) ----------------
__global__ __launch_bounds__(256) void mode_contract(const float* __restrict__ X,
        const float* __restrict__ w_real, const float* __restrict__ w_imag,
        short* __restrict__ C2h, short* __restrict__ C2l) {
    __shared__ float xr[32][128], xi[32][128];
    __shared__ float wr[128][32], wi[128][32];
    const int m = blockIdx.x, h = blockIdx.y, t = threadIdx.x;
    #pragma unroll
    for (int it = 0; it < 16; ++it) {
        int li = t + it * 256;       // 0..4095
        int b = li >> 7, i = li & 127;
        const float2 v = *(const float2*)&X[(size_t)(b * 128 + i) * 128 + 2 * m];
        xr[b][i] = v.x; xi[b][i] = v.y;
        int i2 = li >> 5, o = li & 31;
        size_t off = ((size_t)((h * 128 + i2) * 32 + o)) * NM + m;
        wr[i2][o] = w_real[off];
        wi[i2][o] = w_imag[off];
    }
    __syncthreads();
    const int o = t & 31;
    const int b0 = (t >> 5) * 4;
    float re[4] = {0.f, 0.f, 0.f, 0.f}, im[4] = {0.f, 0.f, 0.f, 0.f};
    for (int i = 0; i < 128; ++i) {
        float wrv = wr[i][o], wiv = wi[i][o];
        #pragma unroll
        for (int j = 0; j < 4; ++j) {
            float a = xr[b0 + j][i], c = xi[b0 + j][i];
            re[j] += a * wrv - c * wiv;
            im[j] += a * wiv + c * wrv;
        }
    }
    const float alpha = (m == 0) ? (1.0f / (float)S_LEN) : (2.0f / (float)S_LEN);
    const int kc = m >> 4;
    const int lk = (2 * m) & 31;
    #pragma unroll
    for (int j = 0; j < 4; ++j) {
        int row = (b0 + j) * 128 + h * 32 + o;
        float vr = alpha * re[j], vi = alpha * im[j];
        unsigned short hr = f2bf(vr), hi_ = f2bf(vi);
        float lr = vr - bf2f(hr), li_ = vi - bf2f(hi_);
        int rb = row >> 7, lr_ = row & 127;
        size_t ui = ((size_t)(rb * 4 + kc) * 4096 + SW32(lr_, lk)) >> 1;   // uint index
        ((unsigned int*)C2h)[ui] = ((unsigned int)hi_ << 16) | hr;
        ((unsigned int*)C2l)[ui] = ((unsigned int)f2bf(li_) << 16) | f2bf(lr);
    }
}

// ---------------- K3: y = C2[4096][128] * Basis[128][8192]; barrier-free K-loop ----------------
// 2048 blocks (64 sb x 32 rb) x 256 thr (4 waves, 2x2 of 64x64).
// A (C2) staged ONCE to LDS (single barrier); B frags reg-loaded from T1frag (L2).
__global__ __launch_bounds__(256, 2) void idft_mfma(const short* __restrict__ C2h,
        const short* __restrict__ C2l, const short* __restrict__ T1fH,
        const short* __restrict__ T1fL, float* __restrict__ y) {
    __shared__ short ah[4][4096], al[4][4096];    // 4 kc tiles x 8KB per half = 64KB
    const int t = threadIdx.x;
    const int lane = t & 63, w = t >> 6;
    const int rl = lane & 15, kq = lane >> 4;
    const int wm = (w >> 1) * 64, wn = (w & 1) * 64;
    const int sb = blockIdx.x, rb = blockIdx.y;

    // stage all of A (C2 row-block, K=128) once
    #pragma unroll
    for (int kc = 0; kc < 4; ++kc) {
        const size_t ta = (size_t)(rb * 4 + kc) * 8192;
        const int wo = w * 2048 + lane * 16;
        glds16((const char*)C2h + ta + wo,        (char*)&ah[kc][0] + w * 2048);
        glds16((const char*)C2h + ta + wo + 1024, (char*)&ah[kc][0] + w * 2048 + 1024);
        glds16((const char*)C2l + ta + wo,        (char*)&al[kc][0] + w * 2048);
        glds16((const char*)C2l + ta + wo + 1024, (char*)&al[kc][0] + w * 2048 + 1024);
    }
    __syncthreads();   // the ONLY barrier

    f4 acc[4][4];
    #pragma unroll
    for (int i = 0; i < 4; ++i)
        #pragma unroll
        for (int j = 0; j < 4; ++j) acc[i][j] = (f4){0.f, 0.f, 0.f, 0.f};

    #pragma unroll
    for (int kc = 0; kc < 4; ++kc) {
        // B fragments straight from L2 (fragment-ordered image)
        s8v Bh[4], Bl[4];
        const size_t tb = (size_t)(sb * 4 + kc) * 8192 + (size_t)rl * 64 + (size_t)kq * 16;
        #pragma unroll
        for (int nf = 0; nf < 4; ++nf) {
            const size_t off = tb + (size_t)(wn + nf * 16) * 64;
            Bh[nf] = *(const s8v*)((const char*)T1fH + off);
            Bl[nf] = *(const s8v*)((const char*)T1fL + off);
        }
        // A fragments from LDS
        const int kk = kq * 8;
        s8v Ah[4], Al[4];
        #pragma unroll
        for (int mf = 0; mf < 4; ++mf) {
            int us = SW32(wm + mf * 16 + rl, kk);
            Ah[mf] = *(const s8v*)&ah[kc][us];
            Al[mf] = *(const s8v*)&al[kc][us];
        }
        #pragma unroll
        for (int mf = 0; mf < 4; ++mf)
            #pragma unroll
            for (int nf = 0; nf < 4; ++nf)
                acc[mf][nf] = __builtin_amdgcn_mfma_f32_16x16x32_bf16(Ah[mf], Bh[nf], acc[mf][nf], 0, 0, 0);
        #pragma unroll
        for (int mf = 0; mf < 4; ++mf)
            #pragma unroll
            for (int nf = 0; nf < 4; ++nf)
                acc[mf][nf] = __builtin_amdgcn_mfma_f32_16x16x32_bf16(Al[mf], Bh[nf], acc[mf][nf], 0, 0, 0);
        #pragma unroll
        for (int mf = 0; mf < 4; ++mf)
            #pragma unroll
            for (int nf = 0; nf < 4; ++nf)
                acc[mf][nf] = __builtin_amdgcn_mfma_f32_16x16x32_bf16(Ah[mf], Bl[nf], acc[mf][nf], 0, 0, 0);
    }

    #pragma unroll
    for (int mf = 0; mf < 4; ++mf) {
        int rr = rb * 128 + wm + mf * 16 + kq * 4;
        #pragma unroll
        for (int nf = 0; nf < 4; ++nf) {
            int c = sb * 128 + wn + nf * 16 + rl;
            #pragma unroll
            for (int r = 0; r < 4; ++r)
                __builtin_nontemporal_store(acc[mf][nf][r], &y[(size_t)(rr + r) * S_LEN + c]);
        }
    }
}

extern "C" void kernel_launch(void* const* d_in, const int* in_sizes, int n_in,
                              void* d_out, int out_size, void* d_ws, size_t ws_size,
                              hipStream_t stream) {
    const float* x      = (const float*)d_in[0];
    const float* w_real = (const float*)d_in[1];
    const float* w_imag = (const float*)d_in[2];
    float* y = (float*)d_out;

    const size_t TBL = (size_t)S_LEN * 128;       // 1M elems
    char* w0 = (char*)d_ws;
    short* T1fH    = (short*)w0;                  // 2MB each half (K3 B fragment image)
    short* T1fL    = T1fH + TBL;
    _Float16* Bimg = (_Float16*)(T1fL + TBL);     // 2MB (K1 B LDS image)
    float* X       = (float*)(Bimg + TBL);        // 2MB
    float* tab     = X + (size_t)4096 * 128;      // 32KB
    float* P       = tab + S_LEN;                 // 16MB (8 slices)
    // C2 overlaps P (disjoint lifetimes: P dead after ksum; C2 born at K2)
    short* C2h     = (short*)P;
    short* C2l     = C2h + TBL;
    const size_t TOTAL = (size_t)((char*)(P + 8 * (size_t)4096 * 128) - w0);  // ~24MB
    if (ws_size < TOTAL) {
        fprintf(stderr, "kernel_launch: ws too small (%zu < %zu bytes)\n", ws_size, TOTAL);
        return;
    }

    gen_master<<<S_LEN / 256, 256, 0, stream>>>(tab);
    gen_tables<<<(S_LEN * 128) / 256, 256, 0, stream>>>(tab, T1fH, T1fL, Bimg);
    dft_fwd_mfma<<<dim3(64, 8), 512, 0, stream>>>(x, Bimg, P);
    ksum<<<512, 256, 0, stream>>>(P, X);
    mode_contract<<<dim3(NM, 4), 256, 0, stream>>>(X, w_real, w_imag, C2h, C2l);
    idft_mfma<<<dim3(64, 32), 256, 0, stream>>>(C2h, C2l, T1fH, T1fL, y);
}